// Round 11
// baseline (403.538 us; speedup 1.0000x reference)
//
#include <hip/hip_runtime.h>

// BinaryConnectNet forward.
// R20 == R19 resubmitted verbatim (R10 bench was an infra failure: container
// acquisition failed twice; kernel never executed — same as R6, where the
// identical resubmit then ran clean).
// R19: k13b widened to 512 threads / 8 waves per image-block.
//  - conv1: 2 threads/pixel (split by pool dy), pair-combined via shfl_xor(1)
//    (max/min assoc-exact -> bit-identical); pack loop split 16/16.
//  - dw-conv/GEMM: wave row map (wid*2+i), i in [0,2): af[2][2], acc[2][4].
//  - tail: 8 chunks x 2048. Same bytes everywhere.
//  - __launch_bounds__(512,8): 4 blk/CU x 8 waves = 32 waves/CU (100% ceiling,
//    was 50%); LDS 4x35KB=141KB fits; VGPR cap 64 == R18 usage, state shrank.
// R18 verified: tail-fusion (kprep inside k13b) kept; barrier-free Os-in-Ps
// epilogue kept; k4a R14 geometry kept; kprep2 separate.
// Math exact; absmax must stay 0.0002441406.

__device__ __forceinline__ int fsign(float v)  { return (v > 0.f) - (v < 0.f); }
__device__ __forceinline__ int dsign(double v) { return (v > 0.0) - (v < 0.0); }

typedef int v4i __attribute__((ext_vector_type(4)));

__device__ __forceinline__ void async16(const signed char* g, signed char* l) {
    __builtin_amdgcn_global_load_lds(
        (const __attribute__((address_space(1))) void*)g,
        (__attribute__((address_space(3))) void*)l, 16, 0, 0);
}

// -------- Prep: conv2-pw sign matrix + adjusted bias b2adj[o] = sign(b)-32*rowsum.
__global__ void kprep2(const float* __restrict__ w2pw, const float* __restrict__ b2pw,
                       signed char* __restrict__ w2s, int* __restrict__ b2adj)
{
    int o = blockIdx.x * 64 + threadIdx.x;   // 256
    int rs = 0;
    for (int cq = 0; cq < 32; cq++) {
        float4 w = *(const float4*)(w2pw + (size_t)o * 128 + cq * 4);
        int s0 = fsign(w.x), s1 = fsign(w.y), s2 = fsign(w.z), s3 = fsign(w.w);
        rs += s0 + s1 + s2 + s3;
        int pk = (s0 & 0xff) | ((s1 & 0xff) << 8) | ((s2 & 0xff) << 16) | ((s3 & 0xff) << 24);
        *(int*)(w2s + (size_t)o * 128 + cq * 4) = pk;
    }
    b2adj[o] = fsign(b2pw[o]) - 32 * rs;
}

// -------- Kernel 13c: conv1 -> Ps -> dw conv2 -> pw MFMA -> hT2 -> kprep tail.
// 512 threads, 8 waves, 1 image/block, grid 1024, 4 blk/CU.
__global__ __launch_bounds__(512, 8) void k13c_fused(
    const float* __restrict__ x,
    const float* __restrict__ w1dw, const float* __restrict__ b1dw,
    const float* __restrict__ w1pw, const float* __restrict__ b1pw,
    const float* __restrict__ w2dw, const float* __restrict__ b2dw,
    const signed char* __restrict__ w2s, const int* __restrict__ b2adj,
    signed char* __restrict__ hT2,
    const float* __restrict__ fc1w, signed char* __restrict__ BL)
{
    __shared__ __align__(16) signed char Ps[32768];
    __shared__ __align__(16) signed char sw4[1152];
    __shared__ signed char sdb2[128];
    __shared__ int sb2adj[256];
    __shared__ float sdw[27], sbdw[3];
    __shared__ unsigned char spidx[128];

    int t = threadIdx.x, l = t & 63, wid = t >> 6;
    int n = blockIdx.x;

    // Phase -1: stage tables.
    if (t < 27) sdw[t] = (float)fsign(w1dw[t]);
    if (t < 3)  sbdw[t] = (float)fsign(b1dw[t]);
    if (t < 128) {
        int b0 = w1pw[t * 3 + 0] > 0.f;
        int b1 = w1pw[t * 3 + 1] > 0.f;
        int b2 = w1pw[t * 3 + 2] > 0.f;
        int b3 = b1pw[t] > 0.f;
        spidx[t] = (unsigned char)(b0 | (b1 << 1) | (b2 << 2) | (b3 << 3));
    }
    for (int i = t; i < 1152; i += 512) {
        int c = i & 127, tap = i >> 7;
        sw4[tap * 128 + c] = (signed char)fsign(w2dw[c * 9 + tap]);
    }
    if (t < 128) sdb2[t] = (signed char)(fsign(b2dw[t]) + 1);
    if (t < 256) sb2adj[t] = b2adj[t];
    __syncthreads();

    // Phase 0: conv1. 2 threads/pixel: pix = t>>1, dy = t&1. Each computes
    // 3 ch x 2 quads (dx), combines maxpool partials with its pair-thread
    // via shfl_xor(1), then writes 16 of the 32 channel-words of Ps row pix.
    {
        int pix = t >> 1, half = t & 1;
        int px = pix & 15, py = pix >> 4;
        int dy = half;
        double h[3][2];
        const float* xb = x + (size_t)n * 3 * 1024;
        #pragma unroll
        for (int c = 0; c < 3; c++) {
            const float* xc = xb + c * 1024;
            #pragma unroll
            for (int dx = 0; dx < 2; dx++) {
                int y = 2 * py + dy, xx = 2 * px + dx;
                double acc = (double)sbdw[c];
                #pragma unroll
                for (int ky = 0; ky < 3; ky++) {
                    int yy = y + ky - 1;
                    if (yy < 0 || yy > 31) continue;
                    #pragma unroll
                    for (int kx = 0; kx < 3; kx++) {
                        int xxx = xx + kx - 1;
                        if (xxx < 0 || xxx > 31) continue;
                        acc += (double)sdw[c * 9 + ky * 3 + kx] * (double)xc[yy * 32 + xxx];
                    }
                }
                h[c][dx] = acc;
            }
        }

        double tv[4][2];
        #pragma unroll
        for (int q = 0; q < 2; q++) {
            double u = h[0][q] + h[1][q];
            double v = h[0][q] - h[1][q];
            tv[0][q] = v - h[2][q];
            tv[1][q] = u - h[2][q];
            tv[2][q] = v + h[2][q];
            tv[3][q] = u + h[2][q];
        }
        int mpack = 0;
        #pragma unroll
        for (int bp = 0; bp < 4; bp++) {
            int mxP = -2, mnP = 2, mxM = -2, mnM = 2;
            #pragma unroll
            for (int q = 0; q < 2; q++) {
                int sP = dsign(tv[bp][q] + 1.0);
                int sM = dsign(tv[bp][q] - 1.0);
                mxP = max(mxP, sP); mnP = min(mnP, sP);
                mxM = max(mxM, sM); mnM = min(mnM, sM);
            }
            // combine with pair thread (other dy) — max/min exact.
            mxP = max(mxP, __shfl_xor(mxP, 1));
            mnP = min(mnP, __shfl_xor(mnP, 1));
            mxM = max(mxM, __shfl_xor(mxM, 1));
            mnM = min(mnM, __shfl_xor(mnM, 1));
            int pat1 = 1 | (bp << 1);
            int pat0 = (~pat1) & 7;
            mpack |= (mxP + 1)   << (2 * (pat1 | 8));
            mpack |= (mxM + 1)   << (2 * pat1);
            mpack |= ((-mnM) + 1) << (2 * (pat0 | 8));
            mpack |= ((-mnP) + 1) << (2 * pat0);
        }

        signed char* prow = Ps + pix * 128;
        const int* pint = (const int*)spidx;
        for (int ob2 = 0; ob2 < 16; ob2++) {
            int ob = half * 16 + ob2;
            int pw = pint[ob];
            int cur = 0;
            #pragma unroll
            for (int e = 0; e < 4; e++) {
                int pi = (pw >> (8 * e)) & 15;
                int mv = ((mpack >> (pi * 2)) & 3) - 1;
                cur |= (mv & 0xff) << (8 * e);
            }
            int ad = (((ob >> 2) ^ (pix & 7)) << 4) + (ob & 3) * 4;
            *(int*)(prow + ad) = cur;
        }
    }
    __syncthreads();

    // Phase 1: depthwise conv2 -> af fragments. 8 waves x 2 row-groups.
    int frow = l & 15;

    v4i af[2][2];
    #pragma unroll
    for (int ks = 0; ks < 2; ks++) {
        int c0 = ks * 64 + (l >> 4) * 16;
        int cc = c0 >> 4;
        int4 w4[9];
        #pragma unroll
        for (int tap = 0; tap < 9; tap++)
            w4[tap] = *(const int4*)&sw4[tap * 128 + c0];
        int4 sdbv = *(const int4*)&sdb2[c0];

        #pragma unroll
        for (int i = 0; i < 2; i++) {
            int r = (wid * 2 + i) * 16 + frow;
            int py = r >> 5, px2 = (r >> 2) & 7, dy = (r >> 1) & 1, dx = r & 1;
            int y = 2 * py + dy, xq = 2 * px2 + dx;
            int4 cnt = (int4){0, 0, 0, 0};
            #pragma unroll
            for (int ky = 0; ky < 3; ky++) {
                int yy = y + ky - 1;
                int yc = min(max(yy, 0), 15);
                #pragma unroll
                for (int kx = 0; kx < 3; kx++) {
                    int xx2 = xq + kx - 1;
                    int xc = min(max(xx2, 0), 15);
                    int inb = ((yy == yc) && (xx2 == xc)) ? 0x01010101 : 0;
                    int p = yc * 16 + xc;
                    int4 v = *(const int4*)&Ps[p * 128 + ((cc ^ (p & 7)) * 16)];
                    int4 w = w4[ky * 3 + kx];
                    cnt.x += ((v.x ^ w.x) >> 1) & inb;
                    cnt.y += ((v.y ^ w.y) >> 1) & inb;
                    cnt.z += ((v.z ^ w.z) >> 1) & inb;
                    cnt.w += ((v.w ^ w.w) >> 1) & inb;
                }
            }
            int valid = (1 + (y > 0) + (y < 15)) * (1 + (xq > 0) + (xq < 15));
            int mb = (valid + 31) * 0x01010101;
            int4 u;
            u.x = sdbv.x + mb - (cnt.x + cnt.x);
            u.y = sdbv.y + mb - (cnt.y + cnt.y);
            u.z = sdbv.z + mb - (cnt.z + cnt.z);
            u.w = sdbv.w + mb - (cnt.w + cnt.w);
            af[i][ks] = (v4i){u.x, u.y, u.z, u.w};
        }
    }
    // All waves done reading Ps before Os planes (inside Ps) are written.
    __syncthreads();

    // Phase 2: pointwise GEMM; Os planes inside dead Ps; barrier-free.
    for (int oc = 0; oc < 4; oc++) {
        v4i acc[2][4];
        #pragma unroll
        for (int i = 0; i < 2; i++)
            #pragma unroll
            for (int jt = 0; jt < 4; jt++) acc[i][jt] = (v4i){0, 0, 0, 0};

        #pragma unroll
        for (int ks = 0; ks < 2; ks++) {
            v4i bf[4];
            #pragma unroll
            for (int jt = 0; jt < 4; jt++)
                bf[jt] = *(const v4i*)(w2s + (size_t)(oc * 64 + jt * 16 + frow) * 128
                                       + ks * 64 + (l >> 4) * 16);
            __builtin_amdgcn_s_setprio(1);
            #pragma unroll
            for (int i = 0; i < 2; i++)
                #pragma unroll
                for (int jt = 0; jt < 4; jt++)
                    acc[i][jt] = __builtin_amdgcn_mfma_i32_16x16x64_i8(af[i][ks], bf[jt], acc[i][jt], 0, 0, 0);
            __builtin_amdgcn_s_setprio(0);
        }

        signed char* Osp = Ps + oc * 5120;   // 64 rows x 80 B
        #pragma unroll
        for (int jt = 0; jt < 4; jt++) {
            int o_l = jt * 16 + frow;
            int bia = sb2adj[oc * 64 + o_l];
            #pragma unroll
            for (int i = 0; i < 2; i++) {
                int mx = -2;
                #pragma unroll
                for (int rr = 0; rr < 4; rr++) {
                    int p = acc[i][jt][rr] + bia;
                    int s = (p > 0) - (p < 0);
                    mx = s > mx ? s : mx;
                }
                int pp = (wid * 2 + i) * 4 + (l >> 4);
                Osp[o_l * 80 + pp] = (signed char)mx;
            }
        }
    }
    __syncthreads();

    // Coalesced copy-out of all 4 planes (1024 int4 over 512 threads).
    #pragma unroll
    for (int rep = 0; rep < 2; rep++) {
        int id = rep * 512 + t;
        int oc = id >> 8, ii = id & 255;
        *(int4*)&hT2[(size_t)n * 16384 + oc * 4096 + ii * 16]
            = *(const int4*)&Ps[oc * 5120 + (ii >> 2) * 80 + (ii & 3) * 16];
    }

    // Phase 3 (tail): fc1_w row n -> 4 radix-128 limbs in BL. Exact math.
    {
        const float* fr = fc1w + (size_t)n * 16384;
        #pragma unroll 2
        for (int kb = 0; kb < 8; kb++) {
            int k0 = kb * 2048 + t * 4;
            float4 w = *(const float4*)(fr + k0);
            float we[4] = {w.x, w.y, w.z, w.w};
            int out[4] = {0, 0, 0, 0};
            #pragma unroll
            for (int e = 0; e < 4; e++) {
                int q = (int)rint((double)we[e] * 4294967296.0);
                q = min(max(q, -266338304), 266338304);
                int d0 = ((q + 64) & 127) - 64; q = (q - d0) >> 7;
                int d1 = ((q + 64) & 127) - 64; q = (q - d1) >> 7;
                int d2 = ((q + 64) & 127) - 64; q = (q - d2) >> 7;
                int d3 = q;
                out[0] |= (d0 & 0xff) << (8 * e);
                out[1] |= (d1 & 0xff) << (8 * e);
                out[2] |= (d2 & 0xff) << (8 * e);
                out[3] |= (d3 & 0xff) << (8 * e);
            }
            #pragma unroll
            for (int m = 0; m < 4; m++)
                *(int*)(BL + (size_t)(n * 4 + m) * 16384 + k0) = out[m];
        }
    }
}

// -------- Kernel 4a: fc1 GEMM (R14 geometry, verified):
// block 128n x 256jm, 8 waves = 2n x 2j x 2 K-phase, wave tile 64n x 128jm,
// K-step 128, dbuf 96 KiB, 1 blk/CU, grid 16x8x2.
__global__ __launch_bounds__(512, 2) void k4a_fc1(
    const signed char* __restrict__ hT2, const signed char* __restrict__ BL,
    double* __restrict__ Pd)
{
    __shared__ __align__(16) signed char smem[98304];  // 2 x (A 16K + B 32K)
    int t = threadIdx.x, l = t & 63, wid = t >> 6;
    int nb0 = blockIdx.y * 128, jb0 = blockIdx.x * 256;
    int kh = blockIdx.z, k0 = kh * 8192;
    int ksw = wid >> 2;                                   // K-phase
    int wn0 = ((wid >> 1) & 1) * 64, wj0 = (wid & 1) * 128;

    int srow = l >> 3;
    int sseg = ((l & 7) ^ srow) * 16;                     // pre-swizzled source
    const signed char* gA = hT2 + (size_t)(nb0 + wid * 16 + srow) * 16384 + k0 + sseg;
    const signed char* gB = BL  + (size_t)(jb0 + wid * 32 + srow) * 16384 + k0 + sseg;

    v4i acc[4][8];
    #pragma unroll
    for (int i = 0; i < 4; i++)
        #pragma unroll
        for (int q = 0; q < 8; q++) acc[i][q] = (v4i){0, 0, 0, 0};

    {   // prologue: stage K-slot 0 into buf0
        signed char* As = smem;
        signed char* Bs = smem + 16384;
        #pragma unroll
        for (int c = 0; c < 2; c++)
            async16(gA + (size_t)c * 8 * 16384, As + (wid * 16 + c * 8) * 128);
        #pragma unroll
        for (int c = 0; c < 4; c++)
            async16(gB + (size_t)c * 8 * 16384, Bs + (wid * 32 + c * 8) * 128);
    }

    int sw = (((ksw * 4) + (l >> 4)) ^ (l & 7)) * 16;     // read swizzle

    for (int it = 0; it < 64; it++) {
        __syncthreads();
        if (it + 1 < 64) {
            int kt = (it + 1) * 128;
            signed char* As = smem + ((it + 1) & 1) * 49152;
            signed char* Bs = As + 16384;
            #pragma unroll
            for (int c = 0; c < 2; c++)
                async16(gA + (size_t)c * 8 * 16384 + kt, As + (wid * 16 + c * 8) * 128);
            #pragma unroll
            for (int c = 0; c < 4; c++)
                async16(gB + (size_t)c * 8 * 16384 + kt, Bs + (wid * 32 + c * 8) * 128);
        }
        const signed char* As = smem + (it & 1) * 49152;
        const signed char* Bs = As + 16384;
        v4i af[4], bf[8];
        #pragma unroll
        for (int i = 0; i < 4; i++)
            af[i] = *(const v4i*)&As[(wn0 + i * 16 + (l & 15)) * 128 + sw];
        #pragma unroll
        for (int q = 0; q < 8; q++)
            bf[q] = *(const v4i*)&Bs[(wj0 + q * 16 + (l & 15)) * 128 + sw];
        #pragma unroll
        for (int i = 0; i < 4; i++)
            #pragma unroll
            for (int q = 0; q < 8; q++)
                acc[i][q] = __builtin_amdgcn_mfma_i32_16x16x64_i8(af[i], bf[q], acc[i][q], 0, 0, 0);
    }

    // Epilogue: combine K-phase wave pairs through 64 KB S, two 64n halves.
    __syncthreads();
    int* S = (int*)smem;                                  // [64 n][256 jm]
    #pragma unroll
    for (int h = 0; h < 2; h++) {
        if (h) __syncthreads();
        if (ksw == 0 && wn0 == h * 64) {
            #pragma unroll
            for (int i = 0; i < 4; i++)
                #pragma unroll
                for (int q = 0; q < 8; q++)
                    #pragma unroll
                    for (int rr = 0; rr < 4; rr++)
                        S[(i * 16 + (l >> 4) * 4 + rr) * 256 + (wj0 + q * 16 + (l & 15))]
                            = acc[i][q][rr];
        }
        __syncthreads();
        if (ksw == 1 && wn0 == h * 64) {
            #pragma unroll
            for (int i = 0; i < 4; i++)
                #pragma unroll
                for (int q = 0; q < 8; q++)
                    #pragma unroll
                    for (int rr = 0; rr < 4; rr++)
                        S[(i * 16 + (l >> 4) * 4 + rr) * 256 + (wj0 + q * 16 + (l & 15))]
                            += acc[i][q][rr];
        }
        __syncthreads();
        #pragma unroll
        for (int e = 0; e < 8; e++) {
            int idx = t * 8 + e;                          // 4096 = 64 n x 64 j
            int n_l = idx >> 6, j_l = idx & 63;
            int4 s = *(const int4*)&S[n_l * 256 + j_l * 4];
            double val = (double)s.x + 128.0 * (double)s.y
                       + 16384.0 * (double)s.z + 2097152.0 * (double)s.w;
            Pd[(size_t)kh * 1048576 + (size_t)(nb0 + h * 64 + n_l) * 1024
               + blockIdx.x * 64 + j_l] = val;
        }
    }
}

// -------- Kernel 45: combine K-halves + bias + sign, then fc2 (block per n).
__global__ __launch_bounds__(256) void k45_comb_fc2(
    const double* __restrict__ Pd, const float* __restrict__ fc1b,
    const float* __restrict__ fc2w, const float* __restrict__ fc2b,
    float* __restrict__ out)
{
    __shared__ double sj[1024];
    __shared__ double pw[4][10];
    int t = threadIdx.x, n = blockIdx.x;
    const double SCALE = 1.0 / 4294967296.0;

    #pragma unroll
    for (int rep = 0; rep < 4; rep++) {
        int j = rep * 256 + t;
        double v = Pd[(size_t)n * 1024 + j] + Pd[1048576 + (size_t)n * 1024 + j];
        double p = v * SCALE + (double)fc1b[j];
        sj[j] = (double)((p > 0.0) - (p < 0.0));
    }
    __syncthreads();

    int j0 = t * 4;
    double s0 = sj[j0], s1 = sj[j0 + 1], s2 = sj[j0 + 2], s3 = sj[j0 + 3];
    double acc[10];
    #pragma unroll
    for (int m = 0; m < 10; m++) {
        float4 w = *(const float4*)(fc2w + (size_t)m * 1024 + j0);
        acc[m] = s0 * (double)w.x + s1 * (double)w.y + s2 * (double)w.z + s3 * (double)w.w;
    }
    #pragma unroll
    for (int off = 32; off > 0; off >>= 1)
        #pragma unroll
        for (int m = 0; m < 10; m++)
            acc[m] += __shfl_down(acc[m], off);
    if ((t & 63) == 0)
        #pragma unroll
        for (int m = 0; m < 10; m++) pw[t >> 6][m] = acc[m];
    __syncthreads();
    if (t < 10)
        out[n * 10 + t] = (float)(pw[0][t] + pw[1][t] + pw[2][t] + pw[3][t] + (double)fc2b[t]);
}

// -------- Fallback (ws too small): R7-style combined k4 + old k5 via hs.
__global__ __launch_bounds__(512) void k4_fc1_mfma(
    const signed char* __restrict__ hT2, const signed char* __restrict__ BL,
    const float* __restrict__ fc1b, signed char* __restrict__ hs)
{
    __shared__ __align__(16) signed char smem[65536];
    int t = threadIdx.x, l = t & 63, wid = t >> 6;
    int nb0 = blockIdx.y * 128, jb0 = blockIdx.x * 128;
    int wn0 = (wid >> 1) * 32;
    int wj0 = (wid & 1) * 64;

    int srow = l >> 3;
    int sseg = ((l & 7) ^ srow) * 16;
    const signed char* gA = hT2 + (size_t)(nb0 + wid * 16 + srow) * 16384 + sseg;
    const signed char* gB = BL  + (size_t)(jb0 + wid * 16 + srow) * 16384 + sseg;

    v4i acc[2][4];
    #pragma unroll
    for (int i = 0; i < 2; i++)
        #pragma unroll
        for (int q = 0; q < 4; q++) acc[i][q] = (v4i){0, 0, 0, 0};

    {
        signed char* As = smem;
        signed char* Bs = smem + 16384;
        #pragma unroll
        for (int i = 0; i < 2; i++) {
            async16(gA + (size_t)i * 8 * 16384, As + (wid * 16 + i * 8) * 128);
            async16(gB + (size_t)i * 8 * 16384, Bs + (wid * 16 + i * 8) * 128);
        }
    }

    for (int it = 0; it < 128; it++) {
        __syncthreads();
        if (it + 1 < 128) {
            int kt = (it + 1) * 128;
            signed char* As = smem + ((it + 1) & 1) * 32768;
            signed char* Bs = As + 16384;
            #pragma unroll
            for (int i = 0; i < 2; i++) {
                async16(gA + (size_t)i * 8 * 16384 + kt, As + (wid * 16 + i * 8) * 128);
                async16(gB + (size_t)i * 8 * 16384 + kt, Bs + (wid * 16 + i * 8) * 128);
            }
        }
        const signed char* As = smem + (it & 1) * 32768;
        const signed char* Bs = As + 16384;
        #pragma unroll
        for (int ks = 0; ks < 2; ks++) {
            int sw = (((ks * 4) + (l >> 4)) ^ (l & 7)) * 16;
            v4i af[2], bf[4];
            #pragma unroll
            for (int i = 0; i < 2; i++)
                af[i] = *(const v4i*)&As[(wn0 + i * 16 + (l & 15)) * 128 + sw];
            #pragma unroll
            for (int q = 0; q < 4; q++)
                bf[q] = *(const v4i*)&Bs[(wj0 + q * 16 + (l & 15)) * 128 + sw];
            #pragma unroll
            for (int i = 0; i < 2; i++)
                #pragma unroll
                for (int q = 0; q < 4; q++)
                    acc[i][q] = __builtin_amdgcn_mfma_i32_16x16x64_i8(af[i], bf[q], acc[i][q], 0, 0, 0);
        }
    }

    __syncthreads();
    int* S = (int*)smem;
    #pragma unroll
    for (int i = 0; i < 2; i++)
        #pragma unroll
        for (int q = 0; q < 4; q++)
            #pragma unroll
            for (int rr = 0; rr < 4; rr++) {
                int n_l  = wn0 + i * 16 + (l >> 4) * 4 + rr;
                int jm_l = wj0 + q * 16 + (l & 15);
                S[n_l * 128 + jm_l] = acc[i][q][rr];
            }
    __syncthreads();

    const double SCALE = 1.0 / 4294967296.0;
    #pragma unroll
    for (int i = 0; i < 8; i++) {
        int idx = t * 8 + i;
        int n_l = idx >> 5, j_l = idx & 31;
        int4 s = *(const int4*)&S[n_l * 128 + j_l * 4];
        double val = (double)s.x + 128.0 * (double)s.y
                   + 16384.0 * (double)s.z + 2097152.0 * (double)s.w;
        int j = blockIdx.x * 32 + j_l;
        double p = val * SCALE + (double)fc1b[j];
        hs[(size_t)(nb0 + n_l) * 1024 + j] = (signed char)((p > 0.0) - (p < 0.0));
    }
}

__global__ void k5_fc2(const signed char* __restrict__ hs,
                       const float* __restrict__ fc2w, const float* __restrict__ fc2b,
                       float* __restrict__ out)
{
    int idx = blockIdx.x * 64 + threadIdx.x;
    if (idx >= 10240) return;
    int n = idx / 10, m = idx - n * 10;
    const signed char* hr = hs + (size_t)n * 1024;
    const float* wr = fc2w + (size_t)m * 1024;
    double acc = (double)fc2b[m];
    for (int jb = 0; jb < 1024; jb += 16) {
        int4 hv = *(const int4*)(hr + jb);
        int wd[4] = {hv.x, hv.y, hv.z, hv.w};
        #pragma unroll
        for (int u = 0; u < 4; u++)
            #pragma unroll
            for (int e = 0; e < 4; e++)
                acc += (double)(signed char)(wd[u] >> (8 * e)) * (double)wr[jb + u * 4 + e];
    }
    out[idx] = (float)acc;
}

extern "C" void kernel_launch(void* const* d_in, const int* in_sizes, int n_in,
                              void* d_out, int out_size, void* d_ws, size_t ws_size,
                              hipStream_t stream)
{
    const float* x    = (const float*)d_in[0];
    const float* w1dw = (const float*)d_in[1];
    const float* b1dw = (const float*)d_in[2];
    const float* w1pw = (const float*)d_in[3];
    const float* b1pw = (const float*)d_in[4];
    const float* w2dw = (const float*)d_in[5];
    const float* b2dw = (const float*)d_in[6];
    const float* w2pw = (const float*)d_in[7];
    const float* b2pw = (const float*)d_in[8];
    const float* fc1w = (const float*)d_in[9];
    const float* fc1b = (const float*)d_in[10];
    const float* fc2w = (const float*)d_in[11];
    const float* fc2b = (const float*)d_in[12];
    float* out = (float*)d_out;

    // workspace:
    //   BL       @0        64MiB   (written by k13c phase 3)
    //   hT2      @64MiB    16MiB
    //   w2s/b2adj@80MiB    33KB    (written by kprep2, read by k13c)
    //   hs       @80MiB+1M 1MiB    (fallback path only)
    //   Pd       @84934656 16MiB   fp64 K-split partials
    char* ws = (char*)d_ws;
    signed char* hT2      = (signed char*)(ws + 67108864);
    signed char* w2s      = (signed char*)(ws + 83886080);
    int*         b2adj    = (int*)(ws + 83886080 + 32768);
    signed char* BL       = (signed char*)(ws);
    signed char* hs       = (signed char*)(ws + 83886080 + 1048576);
    double*      Pd       = (double*)(ws + 84934656);
    bool split = ws_size >= (size_t)84934656 + 16777216;

    hipLaunchKernelGGL(kprep2,     dim3(4),    dim3(64),  0, stream,
                       w2pw, b2pw, w2s, b2adj);
    hipLaunchKernelGGL(k13c_fused, dim3(1024), dim3(512), 0, stream,
                       x, w1dw, b1dw, w1pw, b1pw, w2dw, b2dw, w2s, b2adj, hT2,
                       fc1w, BL);
    if (split) {
        hipLaunchKernelGGL(k4a_fc1,      dim3(16, 8, 2), dim3(512), 0, stream,
                           hT2, BL, Pd);
        hipLaunchKernelGGL(k45_comb_fc2, dim3(1024),     dim3(256), 0, stream,
                           Pd, fc1b, fc2w, fc2b, out);
    } else {
        hipLaunchKernelGGL(k4_fc1_mfma, dim3(32, 8), dim3(512), 0, stream,
                           hT2, BL, fc1b, hs);
        hipLaunchKernelGGL(k5_fc2,      dim3(160),   dim3(64),  0, stream,
                           hs, fc2w, fc2b, out);
    }
}

// Round 12
// 270.755 us; speedup vs baseline: 1.4904x; 1.4904x over previous
//
#include <hip/hip_runtime.h>

// BinaryConnectNet forward.
// R21 == R19/R20 with ONE change: k13c __launch_bounds__(512,8) -> (512,4).
// R20's counters showed the (512,8) bound strangled the unified VGPR/AGPR
// file to 64/wave (32 arch VGPR + 32 AGPR acc) -> conv1's ~30 live doubles
// spilled to scratch: WRITE 415MB/FETCH 240MB (2.3x R18 traffic), 204 us.
// (512,4): 2 blk/CU x 8 waves = 16 waves/CU (same as R18) with 128-VGPR cap
// -> no spill, halved per-thread serial chain measured cleanly.
// All else identical to R20. Math exact; absmax must stay 0.0002441406.

__device__ __forceinline__ int fsign(float v)  { return (v > 0.f) - (v < 0.f); }
__device__ __forceinline__ int dsign(double v) { return (v > 0.0) - (v < 0.0); }

typedef int v4i __attribute__((ext_vector_type(4)));

__device__ __forceinline__ void async16(const signed char* g, signed char* l) {
    __builtin_amdgcn_global_load_lds(
        (const __attribute__((address_space(1))) void*)g,
        (__attribute__((address_space(3))) void*)l, 16, 0, 0);
}

// -------- Prep: conv2-pw sign matrix + adjusted bias b2adj[o] = sign(b)-32*rowsum.
__global__ void kprep2(const float* __restrict__ w2pw, const float* __restrict__ b2pw,
                       signed char* __restrict__ w2s, int* __restrict__ b2adj)
{
    int o = blockIdx.x * 64 + threadIdx.x;   // 256
    int rs = 0;
    for (int cq = 0; cq < 32; cq++) {
        float4 w = *(const float4*)(w2pw + (size_t)o * 128 + cq * 4);
        int s0 = fsign(w.x), s1 = fsign(w.y), s2 = fsign(w.z), s3 = fsign(w.w);
        rs += s0 + s1 + s2 + s3;
        int pk = (s0 & 0xff) | ((s1 & 0xff) << 8) | ((s2 & 0xff) << 16) | ((s3 & 0xff) << 24);
        *(int*)(w2s + (size_t)o * 128 + cq * 4) = pk;
    }
    b2adj[o] = fsign(b2pw[o]) - 32 * rs;
}

// -------- Kernel 13c: conv1 -> Ps -> dw conv2 -> pw MFMA -> hT2 -> kprep tail.
// 512 threads, 8 waves, 1 image/block, grid 1024, 2 blk/CU (128-VGPR cap).
__global__ __launch_bounds__(512, 4) void k13c_fused(
    const float* __restrict__ x,
    const float* __restrict__ w1dw, const float* __restrict__ b1dw,
    const float* __restrict__ w1pw, const float* __restrict__ b1pw,
    const float* __restrict__ w2dw, const float* __restrict__ b2dw,
    const signed char* __restrict__ w2s, const int* __restrict__ b2adj,
    signed char* __restrict__ hT2,
    const float* __restrict__ fc1w, signed char* __restrict__ BL)
{
    __shared__ __align__(16) signed char Ps[32768];
    __shared__ __align__(16) signed char sw4[1152];
    __shared__ signed char sdb2[128];
    __shared__ int sb2adj[256];
    __shared__ float sdw[27], sbdw[3];
    __shared__ unsigned char spidx[128];

    int t = threadIdx.x, l = t & 63, wid = t >> 6;
    int n = blockIdx.x;

    // Phase -1: stage tables.
    if (t < 27) sdw[t] = (float)fsign(w1dw[t]);
    if (t < 3)  sbdw[t] = (float)fsign(b1dw[t]);
    if (t < 128) {
        int b0 = w1pw[t * 3 + 0] > 0.f;
        int b1 = w1pw[t * 3 + 1] > 0.f;
        int b2 = w1pw[t * 3 + 2] > 0.f;
        int b3 = b1pw[t] > 0.f;
        spidx[t] = (unsigned char)(b0 | (b1 << 1) | (b2 << 2) | (b3 << 3));
    }
    for (int i = t; i < 1152; i += 512) {
        int c = i & 127, tap = i >> 7;
        sw4[tap * 128 + c] = (signed char)fsign(w2dw[c * 9 + tap]);
    }
    if (t < 128) sdb2[t] = (signed char)(fsign(b2dw[t]) + 1);
    if (t < 256) sb2adj[t] = b2adj[t];
    __syncthreads();

    // Phase 0: conv1. 2 threads/pixel: pix = t>>1, dy = t&1. Each computes
    // 3 ch x 2 quads (dx), combines maxpool partials with its pair-thread
    // via shfl_xor(1), then writes 16 of the 32 channel-words of Ps row pix.
    {
        int pix = t >> 1, half = t & 1;
        int px = pix & 15, py = pix >> 4;
        int dy = half;
        double h[3][2];
        const float* xb = x + (size_t)n * 3 * 1024;
        #pragma unroll
        for (int c = 0; c < 3; c++) {
            const float* xc = xb + c * 1024;
            #pragma unroll
            for (int dx = 0; dx < 2; dx++) {
                int y = 2 * py + dy, xx = 2 * px + dx;
                double acc = (double)sbdw[c];
                #pragma unroll
                for (int ky = 0; ky < 3; ky++) {
                    int yy = y + ky - 1;
                    if (yy < 0 || yy > 31) continue;
                    #pragma unroll
                    for (int kx = 0; kx < 3; kx++) {
                        int xxx = xx + kx - 1;
                        if (xxx < 0 || xxx > 31) continue;
                        acc += (double)sdw[c * 9 + ky * 3 + kx] * (double)xc[yy * 32 + xxx];
                    }
                }
                h[c][dx] = acc;
            }
        }

        double tv[4][2];
        #pragma unroll
        for (int q = 0; q < 2; q++) {
            double u = h[0][q] + h[1][q];
            double v = h[0][q] - h[1][q];
            tv[0][q] = v - h[2][q];
            tv[1][q] = u - h[2][q];
            tv[2][q] = v + h[2][q];
            tv[3][q] = u + h[2][q];
        }
        int mpack = 0;
        #pragma unroll
        for (int bp = 0; bp < 4; bp++) {
            int mxP = -2, mnP = 2, mxM = -2, mnM = 2;
            #pragma unroll
            for (int q = 0; q < 2; q++) {
                int sP = dsign(tv[bp][q] + 1.0);
                int sM = dsign(tv[bp][q] - 1.0);
                mxP = max(mxP, sP); mnP = min(mnP, sP);
                mxM = max(mxM, sM); mnM = min(mnM, sM);
            }
            // combine with pair thread (other dy) — max/min exact.
            mxP = max(mxP, __shfl_xor(mxP, 1));
            mnP = min(mnP, __shfl_xor(mnP, 1));
            mxM = max(mxM, __shfl_xor(mxM, 1));
            mnM = min(mnM, __shfl_xor(mnM, 1));
            int pat1 = 1 | (bp << 1);
            int pat0 = (~pat1) & 7;
            mpack |= (mxP + 1)   << (2 * (pat1 | 8));
            mpack |= (mxM + 1)   << (2 * pat1);
            mpack |= ((-mnM) + 1) << (2 * (pat0 | 8));
            mpack |= ((-mnP) + 1) << (2 * pat0);
        }

        signed char* prow = Ps + pix * 128;
        const int* pint = (const int*)spidx;
        for (int ob2 = 0; ob2 < 16; ob2++) {
            int ob = half * 16 + ob2;
            int pw = pint[ob];
            int cur = 0;
            #pragma unroll
            for (int e = 0; e < 4; e++) {
                int pi = (pw >> (8 * e)) & 15;
                int mv = ((mpack >> (pi * 2)) & 3) - 1;
                cur |= (mv & 0xff) << (8 * e);
            }
            int ad = (((ob >> 2) ^ (pix & 7)) << 4) + (ob & 3) * 4;
            *(int*)(prow + ad) = cur;
        }
    }
    __syncthreads();

    // Phase 1: depthwise conv2 -> af fragments. 8 waves x 2 row-groups.
    int frow = l & 15;

    v4i af[2][2];
    #pragma unroll
    for (int ks = 0; ks < 2; ks++) {
        int c0 = ks * 64 + (l >> 4) * 16;
        int cc = c0 >> 4;
        int4 w4[9];
        #pragma unroll
        for (int tap = 0; tap < 9; tap++)
            w4[tap] = *(const int4*)&sw4[tap * 128 + c0];
        int4 sdbv = *(const int4*)&sdb2[c0];

        #pragma unroll
        for (int i = 0; i < 2; i++) {
            int r = (wid * 2 + i) * 16 + frow;
            int py = r >> 5, px2 = (r >> 2) & 7, dy = (r >> 1) & 1, dx = r & 1;
            int y = 2 * py + dy, xq = 2 * px2 + dx;
            int4 cnt = (int4){0, 0, 0, 0};
            #pragma unroll
            for (int ky = 0; ky < 3; ky++) {
                int yy = y + ky - 1;
                int yc = min(max(yy, 0), 15);
                #pragma unroll
                for (int kx = 0; kx < 3; kx++) {
                    int xx2 = xq + kx - 1;
                    int xc = min(max(xx2, 0), 15);
                    int inb = ((yy == yc) && (xx2 == xc)) ? 0x01010101 : 0;
                    int p = yc * 16 + xc;
                    int4 v = *(const int4*)&Ps[p * 128 + ((cc ^ (p & 7)) * 16)];
                    int4 w = w4[ky * 3 + kx];
                    cnt.x += ((v.x ^ w.x) >> 1) & inb;
                    cnt.y += ((v.y ^ w.y) >> 1) & inb;
                    cnt.z += ((v.z ^ w.z) >> 1) & inb;
                    cnt.w += ((v.w ^ w.w) >> 1) & inb;
                }
            }
            int valid = (1 + (y > 0) + (y < 15)) * (1 + (xq > 0) + (xq < 15));
            int mb = (valid + 31) * 0x01010101;
            int4 u;
            u.x = sdbv.x + mb - (cnt.x + cnt.x);
            u.y = sdbv.y + mb - (cnt.y + cnt.y);
            u.z = sdbv.z + mb - (cnt.z + cnt.z);
            u.w = sdbv.w + mb - (cnt.w + cnt.w);
            af[i][ks] = (v4i){u.x, u.y, u.z, u.w};
        }
    }
    // All waves done reading Ps before Os planes (inside Ps) are written.
    __syncthreads();

    // Phase 2: pointwise GEMM; Os planes inside dead Ps; barrier-free.
    for (int oc = 0; oc < 4; oc++) {
        v4i acc[2][4];
        #pragma unroll
        for (int i = 0; i < 2; i++)
            #pragma unroll
            for (int jt = 0; jt < 4; jt++) acc[i][jt] = (v4i){0, 0, 0, 0};

        #pragma unroll
        for (int ks = 0; ks < 2; ks++) {
            v4i bf[4];
            #pragma unroll
            for (int jt = 0; jt < 4; jt++)
                bf[jt] = *(const v4i*)(w2s + (size_t)(oc * 64 + jt * 16 + frow) * 128
                                       + ks * 64 + (l >> 4) * 16);
            __builtin_amdgcn_s_setprio(1);
            #pragma unroll
            for (int i = 0; i < 2; i++)
                #pragma unroll
                for (int jt = 0; jt < 4; jt++)
                    acc[i][jt] = __builtin_amdgcn_mfma_i32_16x16x64_i8(af[i][ks], bf[jt], acc[i][jt], 0, 0, 0);
            __builtin_amdgcn_s_setprio(0);
        }

        signed char* Osp = Ps + oc * 5120;   // 64 rows x 80 B
        #pragma unroll
        for (int jt = 0; jt < 4; jt++) {
            int o_l = jt * 16 + frow;
            int bia = sb2adj[oc * 64 + o_l];
            #pragma unroll
            for (int i = 0; i < 2; i++) {
                int mx = -2;
                #pragma unroll
                for (int rr = 0; rr < 4; rr++) {
                    int p = acc[i][jt][rr] + bia;
                    int s = (p > 0) - (p < 0);
                    mx = s > mx ? s : mx;
                }
                int pp = (wid * 2 + i) * 4 + (l >> 4);
                Osp[o_l * 80 + pp] = (signed char)mx;
            }
        }
    }
    __syncthreads();

    // Coalesced copy-out of all 4 planes (1024 int4 over 512 threads).
    #pragma unroll
    for (int rep = 0; rep < 2; rep++) {
        int id = rep * 512 + t;
        int oc = id >> 8, ii = id & 255;
        *(int4*)&hT2[(size_t)n * 16384 + oc * 4096 + ii * 16]
            = *(const int4*)&Ps[oc * 5120 + (ii >> 2) * 80 + (ii & 3) * 16];
    }

    // Phase 3 (tail): fc1_w row n -> 4 radix-128 limbs in BL. Exact math.
    {
        const float* fr = fc1w + (size_t)n * 16384;
        #pragma unroll 2
        for (int kb = 0; kb < 8; kb++) {
            int k0 = kb * 2048 + t * 4;
            float4 w = *(const float4*)(fr + k0);
            float we[4] = {w.x, w.y, w.z, w.w};
            int out[4] = {0, 0, 0, 0};
            #pragma unroll
            for (int e = 0; e < 4; e++) {
                int q = (int)rint((double)we[e] * 4294967296.0);
                q = min(max(q, -266338304), 266338304);
                int d0 = ((q + 64) & 127) - 64; q = (q - d0) >> 7;
                int d1 = ((q + 64) & 127) - 64; q = (q - d1) >> 7;
                int d2 = ((q + 64) & 127) - 64; q = (q - d2) >> 7;
                int d3 = q;
                out[0] |= (d0 & 0xff) << (8 * e);
                out[1] |= (d1 & 0xff) << (8 * e);
                out[2] |= (d2 & 0xff) << (8 * e);
                out[3] |= (d3 & 0xff) << (8 * e);
            }
            #pragma unroll
            for (int m = 0; m < 4; m++)
                *(int*)(BL + (size_t)(n * 4 + m) * 16384 + k0) = out[m];
        }
    }
}

// -------- Kernel 4a: fc1 GEMM (R14 geometry, verified):
// block 128n x 256jm, 8 waves = 2n x 2j x 2 K-phase, wave tile 64n x 128jm,
// K-step 128, dbuf 96 KiB, 1 blk/CU, grid 16x8x2.
__global__ __launch_bounds__(512, 2) void k4a_fc1(
    const signed char* __restrict__ hT2, const signed char* __restrict__ BL,
    double* __restrict__ Pd)
{
    __shared__ __align__(16) signed char smem[98304];  // 2 x (A 16K + B 32K)
    int t = threadIdx.x, l = t & 63, wid = t >> 6;
    int nb0 = blockIdx.y * 128, jb0 = blockIdx.x * 256;
    int kh = blockIdx.z, k0 = kh * 8192;
    int ksw = wid >> 2;                                   // K-phase
    int wn0 = ((wid >> 1) & 1) * 64, wj0 = (wid & 1) * 128;

    int srow = l >> 3;
    int sseg = ((l & 7) ^ srow) * 16;                     // pre-swizzled source
    const signed char* gA = hT2 + (size_t)(nb0 + wid * 16 + srow) * 16384 + k0 + sseg;
    const signed char* gB = BL  + (size_t)(jb0 + wid * 32 + srow) * 16384 + k0 + sseg;

    v4i acc[4][8];
    #pragma unroll
    for (int i = 0; i < 4; i++)
        #pragma unroll
        for (int q = 0; q < 8; q++) acc[i][q] = (v4i){0, 0, 0, 0};

    {   // prologue: stage K-slot 0 into buf0
        signed char* As = smem;
        signed char* Bs = smem + 16384;
        #pragma unroll
        for (int c = 0; c < 2; c++)
            async16(gA + (size_t)c * 8 * 16384, As + (wid * 16 + c * 8) * 128);
        #pragma unroll
        for (int c = 0; c < 4; c++)
            async16(gB + (size_t)c * 8 * 16384, Bs + (wid * 32 + c * 8) * 128);
    }

    int sw = (((ksw * 4) + (l >> 4)) ^ (l & 7)) * 16;     // read swizzle

    for (int it = 0; it < 64; it++) {
        __syncthreads();
        if (it + 1 < 64) {
            int kt = (it + 1) * 128;
            signed char* As = smem + ((it + 1) & 1) * 49152;
            signed char* Bs = As + 16384;
            #pragma unroll
            for (int c = 0; c < 2; c++)
                async16(gA + (size_t)c * 8 * 16384 + kt, As + (wid * 16 + c * 8) * 128);
            #pragma unroll
            for (int c = 0; c < 4; c++)
                async16(gB + (size_t)c * 8 * 16384 + kt, Bs + (wid * 32 + c * 8) * 128);
        }
        const signed char* As = smem + (it & 1) * 49152;
        const signed char* Bs = As + 16384;
        v4i af[4], bf[8];
        #pragma unroll
        for (int i = 0; i < 4; i++)
            af[i] = *(const v4i*)&As[(wn0 + i * 16 + (l & 15)) * 128 + sw];
        #pragma unroll
        for (int q = 0; q < 8; q++)
            bf[q] = *(const v4i*)&Bs[(wj0 + q * 16 + (l & 15)) * 128 + sw];
        #pragma unroll
        for (int i = 0; i < 4; i++)
            #pragma unroll
            for (int q = 0; q < 8; q++)
                acc[i][q] = __builtin_amdgcn_mfma_i32_16x16x64_i8(af[i], bf[q], acc[i][q], 0, 0, 0);
    }

    // Epilogue: combine K-phase wave pairs through 64 KB S, two 64n halves.
    __syncthreads();
    int* S = (int*)smem;                                  // [64 n][256 jm]
    #pragma unroll
    for (int h = 0; h < 2; h++) {
        if (h) __syncthreads();
        if (ksw == 0 && wn0 == h * 64) {
            #pragma unroll
            for (int i = 0; i < 4; i++)
                #pragma unroll
                for (int q = 0; q < 8; q++)
                    #pragma unroll
                    for (int rr = 0; rr < 4; rr++)
                        S[(i * 16 + (l >> 4) * 4 + rr) * 256 + (wj0 + q * 16 + (l & 15))]
                            = acc[i][q][rr];
        }
        __syncthreads();
        if (ksw == 1 && wn0 == h * 64) {
            #pragma unroll
            for (int i = 0; i < 4; i++)
                #pragma unroll
                for (int q = 0; q < 8; q++)
                    #pragma unroll
                    for (int rr = 0; rr < 4; rr++)
                        S[(i * 16 + (l >> 4) * 4 + rr) * 256 + (wj0 + q * 16 + (l & 15))]
                            += acc[i][q][rr];
        }
        __syncthreads();
        #pragma unroll
        for (int e = 0; e < 8; e++) {
            int idx = t * 8 + e;                          // 4096 = 64 n x 64 j
            int n_l = idx >> 6, j_l = idx & 63;
            int4 s = *(const int4*)&S[n_l * 256 + j_l * 4];
            double val = (double)s.x + 128.0 * (double)s.y
                       + 16384.0 * (double)s.z + 2097152.0 * (double)s.w;
            Pd[(size_t)kh * 1048576 + (size_t)(nb0 + h * 64 + n_l) * 1024
               + blockIdx.x * 64 + j_l] = val;
        }
    }
}

// -------- Kernel 45: combine K-halves + bias + sign, then fc2 (block per n).
__global__ __launch_bounds__(256) void k45_comb_fc2(
    const double* __restrict__ Pd, const float* __restrict__ fc1b,
    const float* __restrict__ fc2w, const float* __restrict__ fc2b,
    float* __restrict__ out)
{
    __shared__ double sj[1024];
    __shared__ double pw[4][10];
    int t = threadIdx.x, n = blockIdx.x;
    const double SCALE = 1.0 / 4294967296.0;

    #pragma unroll
    for (int rep = 0; rep < 4; rep++) {
        int j = rep * 256 + t;
        double v = Pd[(size_t)n * 1024 + j] + Pd[1048576 + (size_t)n * 1024 + j];
        double p = v * SCALE + (double)fc1b[j];
        sj[j] = (double)((p > 0.0) - (p < 0.0));
    }
    __syncthreads();

    int j0 = t * 4;
    double s0 = sj[j0], s1 = sj[j0 + 1], s2 = sj[j0 + 2], s3 = sj[j0 + 3];
    double acc[10];
    #pragma unroll
    for (int m = 0; m < 10; m++) {
        float4 w = *(const float4*)(fc2w + (size_t)m * 1024 + j0);
        acc[m] = s0 * (double)w.x + s1 * (double)w.y + s2 * (double)w.z + s3 * (double)w.w;
    }
    #pragma unroll
    for (int off = 32; off > 0; off >>= 1)
        #pragma unroll
        for (int m = 0; m < 10; m++)
            acc[m] += __shfl_down(acc[m], off);
    if ((t & 63) == 0)
        #pragma unroll
        for (int m = 0; m < 10; m++) pw[t >> 6][m] = acc[m];
    __syncthreads();
    if (t < 10)
        out[n * 10 + t] = (float)(pw[0][t] + pw[1][t] + pw[2][t] + pw[3][t] + (double)fc2b[t]);
}

// -------- Fallback (ws too small): R7-style combined k4 + old k5 via hs.
__global__ __launch_bounds__(512) void k4_fc1_mfma(
    const signed char* __restrict__ hT2, const signed char* __restrict__ BL,
    const float* __restrict__ fc1b, signed char* __restrict__ hs)
{
    __shared__ __align__(16) signed char smem[65536];
    int t = threadIdx.x, l = t & 63, wid = t >> 6;
    int nb0 = blockIdx.y * 128, jb0 = blockIdx.x * 128;
    int wn0 = (wid >> 1) * 32;
    int wj0 = (wid & 1) * 64;

    int srow = l >> 3;
    int sseg = ((l & 7) ^ srow) * 16;
    const signed char* gA = hT2 + (size_t)(nb0 + wid * 16 + srow) * 16384 + sseg;
    const signed char* gB = BL  + (size_t)(jb0 + wid * 16 + srow) * 16384 + sseg;

    v4i acc[2][4];
    #pragma unroll
    for (int i = 0; i < 2; i++)
        #pragma unroll
        for (int q = 0; q < 4; q++) acc[i][q] = (v4i){0, 0, 0, 0};

    {
        signed char* As = smem;
        signed char* Bs = smem + 16384;
        #pragma unroll
        for (int i = 0; i < 2; i++) {
            async16(gA + (size_t)i * 8 * 16384, As + (wid * 16 + i * 8) * 128);
            async16(gB + (size_t)i * 8 * 16384, Bs + (wid * 16 + i * 8) * 128);
        }
    }

    for (int it = 0; it < 128; it++) {
        __syncthreads();
        if (it + 1 < 128) {
            int kt = (it + 1) * 128;
            signed char* As = smem + ((it + 1) & 1) * 32768;
            signed char* Bs = As + 16384;
            #pragma unroll
            for (int i = 0; i < 2; i++) {
                async16(gA + (size_t)i * 8 * 16384 + kt, As + (wid * 16 + i * 8) * 128);
                async16(gB + (size_t)i * 8 * 16384 + kt, Bs + (wid * 16 + i * 8) * 128);
            }
        }
        const signed char* As = smem + (it & 1) * 32768;
        const signed char* Bs = As + 16384;
        #pragma unroll
        for (int ks = 0; ks < 2; ks++) {
            int sw = (((ks * 4) + (l >> 4)) ^ (l & 7)) * 16;
            v4i af[2], bf[4];
            #pragma unroll
            for (int i = 0; i < 2; i++)
                af[i] = *(const v4i*)&As[(wn0 + i * 16 + (l & 15)) * 128 + sw];
            #pragma unroll
            for (int q = 0; q < 4; q++)
                bf[q] = *(const v4i*)&Bs[(wj0 + q * 16 + (l & 15)) * 128 + sw];
            #pragma unroll
            for (int i = 0; i < 2; i++)
                #pragma unroll
                for (int q = 0; q < 4; q++)
                    acc[i][q] = __builtin_amdgcn_mfma_i32_16x16x64_i8(af[i], bf[q], acc[i][q], 0, 0, 0);
        }
    }

    __syncthreads();
    int* S = (int*)smem;
    #pragma unroll
    for (int i = 0; i < 2; i++)
        #pragma unroll
        for (int q = 0; q < 4; q++)
            #pragma unroll
            for (int rr = 0; rr < 4; rr++) {
                int n_l  = wn0 + i * 16 + (l >> 4) * 4 + rr;
                int jm_l = wj0 + q * 16 + (l & 15);
                S[n_l * 128 + jm_l] = acc[i][q][rr];
            }
    __syncthreads();

    const double SCALE = 1.0 / 4294967296.0;
    #pragma unroll
    for (int i = 0; i < 8; i++) {
        int idx = t * 8 + i;
        int n_l = idx >> 5, j_l = idx & 31;
        int4 s = *(const int4*)&S[n_l * 128 + j_l * 4];
        double val = (double)s.x + 128.0 * (double)s.y
                   + 16384.0 * (double)s.z + 2097152.0 * (double)s.w;
        int j = blockIdx.x * 32 + j_l;
        double p = val * SCALE + (double)fc1b[j];
        hs[(size_t)(nb0 + n_l) * 1024 + j] = (signed char)((p > 0.0) - (p < 0.0));
    }
}

__global__ void k5_fc2(const signed char* __restrict__ hs,
                       const float* __restrict__ fc2w, const float* __restrict__ fc2b,
                       float* __restrict__ out)
{
    int idx = blockIdx.x * 64 + threadIdx.x;
    if (idx >= 10240) return;
    int n = idx / 10, m = idx - n * 10;
    const signed char* hr = hs + (size_t)n * 1024;
    const float* wr = fc2w + (size_t)m * 1024;
    double acc = (double)fc2b[m];
    for (int jb = 0; jb < 1024; jb += 16) {
        int4 hv = *(const int4*)(hr + jb);
        int wd[4] = {hv.x, hv.y, hv.z, hv.w};
        #pragma unroll
        for (int u = 0; u < 4; u++)
            #pragma unroll
            for (int e = 0; e < 4; e++)
                acc += (double)(signed char)(wd[u] >> (8 * e)) * (double)wr[jb + u * 4 + e];
    }
    out[idx] = (float)acc;
}

extern "C" void kernel_launch(void* const* d_in, const int* in_sizes, int n_in,
                              void* d_out, int out_size, void* d_ws, size_t ws_size,
                              hipStream_t stream)
{
    const float* x    = (const float*)d_in[0];
    const float* w1dw = (const float*)d_in[1];
    const float* b1dw = (const float*)d_in[2];
    const float* w1pw = (const float*)d_in[3];
    const float* b1pw = (const float*)d_in[4];
    const float* w2dw = (const float*)d_in[5];
    const float* b2dw = (const float*)d_in[6];
    const float* w2pw = (const float*)d_in[7];
    const float* b2pw = (const float*)d_in[8];
    const float* fc1w = (const float*)d_in[9];
    const float* fc1b = (const float*)d_in[10];
    const float* fc2w = (const float*)d_in[11];
    const float* fc2b = (const float*)d_in[12];
    float* out = (float*)d_out;

    // workspace:
    //   BL       @0        64MiB   (written by k13c phase 3)
    //   hT2      @64MiB    16MiB
    //   w2s/b2adj@80MiB    33KB    (written by kprep2, read by k13c)
    //   hs       @80MiB+1M 1MiB    (fallback path only)
    //   Pd       @84934656 16MiB   fp64 K-split partials
    char* ws = (char*)d_ws;
    signed char* hT2      = (signed char*)(ws + 67108864);
    signed char* w2s      = (signed char*)(ws + 83886080);
    int*         b2adj    = (int*)(ws + 83886080 + 32768);
    signed char* BL       = (signed char*)(ws);
    signed char* hs       = (signed char*)(ws + 83886080 + 1048576);
    double*      Pd       = (double*)(ws + 84934656);
    bool split = ws_size >= (size_t)84934656 + 16777216;

    hipLaunchKernelGGL(kprep2,     dim3(4),    dim3(64),  0, stream,
                       w2pw, b2pw, w2s, b2adj);
    hipLaunchKernelGGL(k13c_fused, dim3(1024), dim3(512), 0, stream,
                       x, w1dw, b1dw, w1pw, b1pw, w2dw, b2dw, w2s, b2adj, hT2,
                       fc1w, BL);
    if (split) {
        hipLaunchKernelGGL(k4a_fc1,      dim3(16, 8, 2), dim3(512), 0, stream,
                           hT2, BL, Pd);
        hipLaunchKernelGGL(k45_comb_fc2, dim3(1024),     dim3(256), 0, stream,
                           Pd, fc1b, fc2w, fc2b, out);
    } else {
        hipLaunchKernelGGL(k4_fc1_mfma, dim3(32, 8), dim3(512), 0, stream,
                           hT2, BL, fc1b, hs);
        hipLaunchKernelGGL(k5_fc2,      dim3(160),   dim3(64),  0, stream,
                           hs, fc2w, fc2b, out);
    }
}

// Round 13
// 263.416 us; speedup vs baseline: 1.5319x; 1.0279x over previous
//
#include <hip/hip_runtime.h>

// BinaryConnectNet forward.
// R22: k13c Phase-0 x-through-LDS. conv1 previously issued ~54 scattered
// global f32 loads/thread (L2 ~200cyc chains); now the 12 KB image is staged
// COALESCED into the front of Ps (float4), conv taps read from LDS (~6cyc,
// ~2-way conflicts = free), and Ps output rows overwrite the image only
// after a barrier fences the last x read. Zero LDS growth. All else
// byte-identical to R21 (512thr/(512,4), tail-fusion, barrier-free Os-in-Ps,
// k4a R14 geometry). Math exact; absmax must stay 0.0002441406.

__device__ __forceinline__ int fsign(float v)  { return (v > 0.f) - (v < 0.f); }
__device__ __forceinline__ int dsign(double v) { return (v > 0.0) - (v < 0.0); }

typedef int v4i __attribute__((ext_vector_type(4)));

__device__ __forceinline__ void async16(const signed char* g, signed char* l) {
    __builtin_amdgcn_global_load_lds(
        (const __attribute__((address_space(1))) void*)g,
        (__attribute__((address_space(3))) void*)l, 16, 0, 0);
}

// -------- Prep: conv2-pw sign matrix + adjusted bias b2adj[o] = sign(b)-32*rowsum.
__global__ void kprep2(const float* __restrict__ w2pw, const float* __restrict__ b2pw,
                       signed char* __restrict__ w2s, int* __restrict__ b2adj)
{
    int o = blockIdx.x * 64 + threadIdx.x;   // 256
    int rs = 0;
    for (int cq = 0; cq < 32; cq++) {
        float4 w = *(const float4*)(w2pw + (size_t)o * 128 + cq * 4);
        int s0 = fsign(w.x), s1 = fsign(w.y), s2 = fsign(w.z), s3 = fsign(w.w);
        rs += s0 + s1 + s2 + s3;
        int pk = (s0 & 0xff) | ((s1 & 0xff) << 8) | ((s2 & 0xff) << 16) | ((s3 & 0xff) << 24);
        *(int*)(w2s + (size_t)o * 128 + cq * 4) = pk;
    }
    b2adj[o] = fsign(b2pw[o]) - 32 * rs;
}

// -------- Kernel 13c: conv1 -> Ps -> dw conv2 -> pw MFMA -> hT2 -> kprep tail.
// 512 threads, 8 waves, 1 image/block, grid 1024, (512,4) = 128-VGPR cap.
__global__ __launch_bounds__(512, 4) void k13c_fused(
    const float* __restrict__ x,
    const float* __restrict__ w1dw, const float* __restrict__ b1dw,
    const float* __restrict__ w1pw, const float* __restrict__ b1pw,
    const float* __restrict__ w2dw, const float* __restrict__ b2dw,
    const signed char* __restrict__ w2s, const int* __restrict__ b2adj,
    signed char* __restrict__ hT2,
    const float* __restrict__ fc1w, signed char* __restrict__ BL)
{
    __shared__ __align__(16) signed char Ps[32768];
    __shared__ __align__(16) signed char sw4[1152];
    __shared__ signed char sdb2[128];
    __shared__ int sb2adj[256];
    __shared__ float sdw[27], sbdw[3];
    __shared__ unsigned char spidx[128];

    int t = threadIdx.x, l = t & 63, wid = t >> 6;
    int n = blockIdx.x;

    // Phase -1: stage tables AND the x image (12 KB) into the front of Ps.
    if (t < 27) sdw[t] = (float)fsign(w1dw[t]);
    if (t < 3)  sbdw[t] = (float)fsign(b1dw[t]);
    if (t < 128) {
        int b0 = w1pw[t * 3 + 0] > 0.f;
        int b1 = w1pw[t * 3 + 1] > 0.f;
        int b2 = w1pw[t * 3 + 2] > 0.f;
        int b3 = b1pw[t] > 0.f;
        spidx[t] = (unsigned char)(b0 | (b1 << 1) | (b2 << 2) | (b3 << 3));
    }
    for (int i = t; i < 1152; i += 512) {
        int c = i & 127, tap = i >> 7;
        sw4[tap * 128 + c] = (signed char)fsign(w2dw[c * 9 + tap]);
    }
    if (t < 128) sdb2[t] = (signed char)(fsign(b2dw[t]) + 1);
    if (t < 256) sb2adj[t] = b2adj[t];
    {
        float4* xf4 = (float4*)Ps;                         // 768 float4 = 12 KB
        const float4* xg4 = (const float4*)(x + (size_t)n * 3072);
        for (int i = t; i < 768; i += 512)
            xf4[i] = xg4[i];
    }
    __syncthreads();

    // Phase 0: conv1 from LDS image. 2 threads/pixel: pix=t>>1, dy=t&1.
    // Compute h fully, barrier (fences x reads), THEN overwrite Ps rows.
    {
        int pix = t >> 1, half = t & 1;
        int px = pix & 15, py = pix >> 4;
        int dy = half;
        double h[3][2];
        const float* xb = (const float*)Ps;                // [c][32][32] staged
        #pragma unroll
        for (int c = 0; c < 3; c++) {
            const float* xc = xb + c * 1024;
            #pragma unroll
            for (int dx = 0; dx < 2; dx++) {
                int y = 2 * py + dy, xx = 2 * px + dx;
                double acc = (double)sbdw[c];
                #pragma unroll
                for (int ky = 0; ky < 3; ky++) {
                    int yy = y + ky - 1;
                    if (yy < 0 || yy > 31) continue;
                    #pragma unroll
                    for (int kx = 0; kx < 3; kx++) {
                        int xxx = xx + kx - 1;
                        if (xxx < 0 || xxx > 31) continue;
                        acc += (double)sdw[c * 9 + ky * 3 + kx] * (double)xc[yy * 32 + xxx];
                    }
                }
                h[c][dx] = acc;
            }
        }

        double tv[4][2];
        #pragma unroll
        for (int q = 0; q < 2; q++) {
            double u = h[0][q] + h[1][q];
            double v = h[0][q] - h[1][q];
            tv[0][q] = v - h[2][q];
            tv[1][q] = u - h[2][q];
            tv[2][q] = v + h[2][q];
            tv[3][q] = u + h[2][q];
        }
        int mpack = 0;
        #pragma unroll
        for (int bp = 0; bp < 4; bp++) {
            int mxP = -2, mnP = 2, mxM = -2, mnM = 2;
            #pragma unroll
            for (int q = 0; q < 2; q++) {
                int sP = dsign(tv[bp][q] + 1.0);
                int sM = dsign(tv[bp][q] - 1.0);
                mxP = max(mxP, sP); mnP = min(mnP, sP);
                mxM = max(mxM, sM); mnM = min(mnM, sM);
            }
            // combine with pair thread (other dy) — max/min exact.
            mxP = max(mxP, __shfl_xor(mxP, 1));
            mnP = min(mnP, __shfl_xor(mnP, 1));
            mxM = max(mxM, __shfl_xor(mxM, 1));
            mnM = min(mnM, __shfl_xor(mnM, 1));
            int pat1 = 1 | (bp << 1);
            int pat0 = (~pat1) & 7;
            mpack |= (mxP + 1)   << (2 * (pat1 | 8));
            mpack |= (mxM + 1)   << (2 * pat1);
            mpack |= ((-mnM) + 1) << (2 * (pat0 | 8));
            mpack |= ((-mnP) + 1) << (2 * pat0);
        }

        // All x reads are complete on every thread; safe to overwrite Ps.
        __syncthreads();

        signed char* prow = Ps + pix * 128;
        const int* pint = (const int*)spidx;
        for (int ob2 = 0; ob2 < 16; ob2++) {
            int ob = half * 16 + ob2;
            int pw = pint[ob];
            int cur = 0;
            #pragma unroll
            for (int e = 0; e < 4; e++) {
                int pi = (pw >> (8 * e)) & 15;
                int mv = ((mpack >> (pi * 2)) & 3) - 1;
                cur |= (mv & 0xff) << (8 * e);
            }
            int ad = (((ob >> 2) ^ (pix & 7)) << 4) + (ob & 3) * 4;
            *(int*)(prow + ad) = cur;
        }
    }
    __syncthreads();

    // Phase 1: depthwise conv2 -> af fragments. 8 waves x 2 row-groups.
    int frow = l & 15;

    v4i af[2][2];
    #pragma unroll
    for (int ks = 0; ks < 2; ks++) {
        int c0 = ks * 64 + (l >> 4) * 16;
        int cc = c0 >> 4;
        int4 w4[9];
        #pragma unroll
        for (int tap = 0; tap < 9; tap++)
            w4[tap] = *(const int4*)&sw4[tap * 128 + c0];
        int4 sdbv = *(const int4*)&sdb2[c0];

        #pragma unroll
        for (int i = 0; i < 2; i++) {
            int r = (wid * 2 + i) * 16 + frow;
            int py = r >> 5, px2 = (r >> 2) & 7, dy = (r >> 1) & 1, dx = r & 1;
            int y = 2 * py + dy, xq = 2 * px2 + dx;
            int4 cnt = (int4){0, 0, 0, 0};
            #pragma unroll
            for (int ky = 0; ky < 3; ky++) {
                int yy = y + ky - 1;
                int yc = min(max(yy, 0), 15);
                #pragma unroll
                for (int kx = 0; kx < 3; kx++) {
                    int xx2 = xq + kx - 1;
                    int xc = min(max(xx2, 0), 15);
                    int inb = ((yy == yc) && (xx2 == xc)) ? 0x01010101 : 0;
                    int p = yc * 16 + xc;
                    int4 v = *(const int4*)&Ps[p * 128 + ((cc ^ (p & 7)) * 16)];
                    int4 w = w4[ky * 3 + kx];
                    cnt.x += ((v.x ^ w.x) >> 1) & inb;
                    cnt.y += ((v.y ^ w.y) >> 1) & inb;
                    cnt.z += ((v.z ^ w.z) >> 1) & inb;
                    cnt.w += ((v.w ^ w.w) >> 1) & inb;
                }
            }
            int valid = (1 + (y > 0) + (y < 15)) * (1 + (xq > 0) + (xq < 15));
            int mb = (valid + 31) * 0x01010101;
            int4 u;
            u.x = sdbv.x + mb - (cnt.x + cnt.x);
            u.y = sdbv.y + mb - (cnt.y + cnt.y);
            u.z = sdbv.z + mb - (cnt.z + cnt.z);
            u.w = sdbv.w + mb - (cnt.w + cnt.w);
            af[i][ks] = (v4i){u.x, u.y, u.z, u.w};
        }
    }
    // All waves done reading Ps before Os planes (inside Ps) are written.
    __syncthreads();

    // Phase 2: pointwise GEMM; Os planes inside dead Ps; barrier-free.
    for (int oc = 0; oc < 4; oc++) {
        v4i acc[2][4];
        #pragma unroll
        for (int i = 0; i < 2; i++)
            #pragma unroll
            for (int jt = 0; jt < 4; jt++) acc[i][jt] = (v4i){0, 0, 0, 0};

        #pragma unroll
        for (int ks = 0; ks < 2; ks++) {
            v4i bf[4];
            #pragma unroll
            for (int jt = 0; jt < 4; jt++)
                bf[jt] = *(const v4i*)(w2s + (size_t)(oc * 64 + jt * 16 + frow) * 128
                                       + ks * 64 + (l >> 4) * 16);
            __builtin_amdgcn_s_setprio(1);
            #pragma unroll
            for (int i = 0; i < 2; i++)
                #pragma unroll
                for (int jt = 0; jt < 4; jt++)
                    acc[i][jt] = __builtin_amdgcn_mfma_i32_16x16x64_i8(af[i][ks], bf[jt], acc[i][jt], 0, 0, 0);
            __builtin_amdgcn_s_setprio(0);
        }

        signed char* Osp = Ps + oc * 5120;   // 64 rows x 80 B
        #pragma unroll
        for (int jt = 0; jt < 4; jt++) {
            int o_l = jt * 16 + frow;
            int bia = sb2adj[oc * 64 + o_l];
            #pragma unroll
            for (int i = 0; i < 2; i++) {
                int mx = -2;
                #pragma unroll
                for (int rr = 0; rr < 4; rr++) {
                    int p = acc[i][jt][rr] + bia;
                    int s = (p > 0) - (p < 0);
                    mx = s > mx ? s : mx;
                }
                int pp = (wid * 2 + i) * 4 + (l >> 4);
                Osp[o_l * 80 + pp] = (signed char)mx;
            }
        }
    }
    __syncthreads();

    // Coalesced copy-out of all 4 planes (1024 int4 over 512 threads).
    #pragma unroll
    for (int rep = 0; rep < 2; rep++) {
        int id = rep * 512 + t;
        int oc = id >> 8, ii = id & 255;
        *(int4*)&hT2[(size_t)n * 16384 + oc * 4096 + ii * 16]
            = *(const int4*)&Ps[oc * 5120 + (ii >> 2) * 80 + (ii & 3) * 16];
    }

    // Phase 3 (tail): fc1_w row n -> 4 radix-128 limbs in BL. Exact math.
    {
        const float* fr = fc1w + (size_t)n * 16384;
        #pragma unroll 2
        for (int kb = 0; kb < 8; kb++) {
            int k0 = kb * 2048 + t * 4;
            float4 w = *(const float4*)(fr + k0);
            float we[4] = {w.x, w.y, w.z, w.w};
            int out[4] = {0, 0, 0, 0};
            #pragma unroll
            for (int e = 0; e < 4; e++) {
                int q = (int)rint((double)we[e] * 4294967296.0);
                q = min(max(q, -266338304), 266338304);
                int d0 = ((q + 64) & 127) - 64; q = (q - d0) >> 7;
                int d1 = ((q + 64) & 127) - 64; q = (q - d1) >> 7;
                int d2 = ((q + 64) & 127) - 64; q = (q - d2) >> 7;
                int d3 = q;
                out[0] |= (d0 & 0xff) << (8 * e);
                out[1] |= (d1 & 0xff) << (8 * e);
                out[2] |= (d2 & 0xff) << (8 * e);
                out[3] |= (d3 & 0xff) << (8 * e);
            }
            #pragma unroll
            for (int m = 0; m < 4; m++)
                *(int*)(BL + (size_t)(n * 4 + m) * 16384 + k0) = out[m];
        }
    }
}

// -------- Kernel 4a: fc1 GEMM (R14 geometry, verified):
// block 128n x 256jm, 8 waves = 2n x 2j x 2 K-phase, wave tile 64n x 128jm,
// K-step 128, dbuf 96 KiB, 1 blk/CU, grid 16x8x2.
__global__ __launch_bounds__(512, 2) void k4a_fc1(
    const signed char* __restrict__ hT2, const signed char* __restrict__ BL,
    double* __restrict__ Pd)
{
    __shared__ __align__(16) signed char smem[98304];  // 2 x (A 16K + B 32K)
    int t = threadIdx.x, l = t & 63, wid = t >> 6;
    int nb0 = blockIdx.y * 128, jb0 = blockIdx.x * 256;
    int kh = blockIdx.z, k0 = kh * 8192;
    int ksw = wid >> 2;                                   // K-phase
    int wn0 = ((wid >> 1) & 1) * 64, wj0 = (wid & 1) * 128;

    int srow = l >> 3;
    int sseg = ((l & 7) ^ srow) * 16;                     // pre-swizzled source
    const signed char* gA = hT2 + (size_t)(nb0 + wid * 16 + srow) * 16384 + k0 + sseg;
    const signed char* gB = BL  + (size_t)(jb0 + wid * 32 + srow) * 16384 + k0 + sseg;

    v4i acc[4][8];
    #pragma unroll
    for (int i = 0; i < 4; i++)
        #pragma unroll
        for (int q = 0; q < 8; q++) acc[i][q] = (v4i){0, 0, 0, 0};

    {   // prologue: stage K-slot 0 into buf0
        signed char* As = smem;
        signed char* Bs = smem + 16384;
        #pragma unroll
        for (int c = 0; c < 2; c++)
            async16(gA + (size_t)c * 8 * 16384, As + (wid * 16 + c * 8) * 128);
        #pragma unroll
        for (int c = 0; c < 4; c++)
            async16(gB + (size_t)c * 8 * 16384, Bs + (wid * 32 + c * 8) * 128);
    }

    int sw = (((ksw * 4) + (l >> 4)) ^ (l & 7)) * 16;     // read swizzle

    for (int it = 0; it < 64; it++) {
        __syncthreads();
        if (it + 1 < 64) {
            int kt = (it + 1) * 128;
            signed char* As = smem + ((it + 1) & 1) * 49152;
            signed char* Bs = As + 16384;
            #pragma unroll
            for (int c = 0; c < 2; c++)
                async16(gA + (size_t)c * 8 * 16384 + kt, As + (wid * 16 + c * 8) * 128);
            #pragma unroll
            for (int c = 0; c < 4; c++)
                async16(gB + (size_t)c * 8 * 16384 + kt, Bs + (wid * 32 + c * 8) * 128);
        }
        const signed char* As = smem + (it & 1) * 49152;
        const signed char* Bs = As + 16384;
        v4i af[4], bf[8];
        #pragma unroll
        for (int i = 0; i < 4; i++)
            af[i] = *(const v4i*)&As[(wn0 + i * 16 + (l & 15)) * 128 + sw];
        #pragma unroll
        for (int q = 0; q < 8; q++)
            bf[q] = *(const v4i*)&Bs[(wj0 + q * 16 + (l & 15)) * 128 + sw];
        #pragma unroll
        for (int i = 0; i < 4; i++)
            #pragma unroll
            for (int q = 0; q < 8; q++)
                acc[i][q] = __builtin_amdgcn_mfma_i32_16x16x64_i8(af[i], bf[q], acc[i][q], 0, 0, 0);
    }

    // Epilogue: combine K-phase wave pairs through 64 KB S, two 64n halves.
    __syncthreads();
    int* S = (int*)smem;                                  // [64 n][256 jm]
    #pragma unroll
    for (int h = 0; h < 2; h++) {
        if (h) __syncthreads();
        if (ksw == 0 && wn0 == h * 64) {
            #pragma unroll
            for (int i = 0; i < 4; i++)
                #pragma unroll
                for (int q = 0; q < 8; q++)
                    #pragma unroll
                    for (int rr = 0; rr < 4; rr++)
                        S[(i * 16 + (l >> 4) * 4 + rr) * 256 + (wj0 + q * 16 + (l & 15))]
                            = acc[i][q][rr];
        }
        __syncthreads();
        if (ksw == 1 && wn0 == h * 64) {
            #pragma unroll
            for (int i = 0; i < 4; i++)
                #pragma unroll
                for (int q = 0; q < 8; q++)
                    #pragma unroll
                    for (int rr = 0; rr < 4; rr++)
                        S[(i * 16 + (l >> 4) * 4 + rr) * 256 + (wj0 + q * 16 + (l & 15))]
                            += acc[i][q][rr];
        }
        __syncthreads();
        #pragma unroll
        for (int e = 0; e < 8; e++) {
            int idx = t * 8 + e;                          // 4096 = 64 n x 64 j
            int n_l = idx >> 6, j_l = idx & 63;
            int4 s = *(const int4*)&S[n_l * 256 + j_l * 4];
            double val = (double)s.x + 128.0 * (double)s.y
                       + 16384.0 * (double)s.z + 2097152.0 * (double)s.w;
            Pd[(size_t)kh * 1048576 + (size_t)(nb0 + h * 64 + n_l) * 1024
               + blockIdx.x * 64 + j_l] = val;
        }
    }
}

// -------- Kernel 45: combine K-halves + bias + sign, then fc2 (block per n).
__global__ __launch_bounds__(256) void k45_comb_fc2(
    const double* __restrict__ Pd, const float* __restrict__ fc1b,
    const float* __restrict__ fc2w, const float* __restrict__ fc2b,
    float* __restrict__ out)
{
    __shared__ double sj[1024];
    __shared__ double pw[4][10];
    int t = threadIdx.x, n = blockIdx.x;
    const double SCALE = 1.0 / 4294967296.0;

    #pragma unroll
    for (int rep = 0; rep < 4; rep++) {
        int j = rep * 256 + t;
        double v = Pd[(size_t)n * 1024 + j] + Pd[1048576 + (size_t)n * 1024 + j];
        double p = v * SCALE + (double)fc1b[j];
        sj[j] = (double)((p > 0.0) - (p < 0.0));
    }
    __syncthreads();

    int j0 = t * 4;
    double s0 = sj[j0], s1 = sj[j0 + 1], s2 = sj[j0 + 2], s3 = sj[j0 + 3];
    double acc[10];
    #pragma unroll
    for (int m = 0; m < 10; m++) {
        float4 w = *(const float4*)(fc2w + (size_t)m * 1024 + j0);
        acc[m] = s0 * (double)w.x + s1 * (double)w.y + s2 * (double)w.z + s3 * (double)w.w;
    }
    #pragma unroll
    for (int off = 32; off > 0; off >>= 1)
        #pragma unroll
        for (int m = 0; m < 10; m++)
            acc[m] += __shfl_down(acc[m], off);
    if ((t & 63) == 0)
        #pragma unroll
        for (int m = 0; m < 10; m++) pw[t >> 6][m] = acc[m];
    __syncthreads();
    if (t < 10)
        out[n * 10 + t] = (float)(pw[0][t] + pw[1][t] + pw[2][t] + pw[3][t] + (double)fc2b[t]);
}

// -------- Fallback (ws too small): R7-style combined k4 + old k5 via hs.
__global__ __launch_bounds__(512) void k4_fc1_mfma(
    const signed char* __restrict__ hT2, const signed char* __restrict__ BL,
    const float* __restrict__ fc1b, signed char* __restrict__ hs)
{
    __shared__ __align__(16) signed char smem[65536];
    int t = threadIdx.x, l = t & 63, wid = t >> 6;
    int nb0 = blockIdx.y * 128, jb0 = blockIdx.x * 128;
    int wn0 = (wid >> 1) * 32;
    int wj0 = (wid & 1) * 64;

    int srow = l >> 3;
    int sseg = ((l & 7) ^ srow) * 16;
    const signed char* gA = hT2 + (size_t)(nb0 + wid * 16 + srow) * 16384 + sseg;
    const signed char* gB = BL  + (size_t)(jb0 + wid * 16 + srow) * 16384 + sseg;

    v4i acc[2][4];
    #pragma unroll
    for (int i = 0; i < 2; i++)
        #pragma unroll
        for (int q = 0; q < 4; q++) acc[i][q] = (v4i){0, 0, 0, 0};

    {
        signed char* As = smem;
        signed char* Bs = smem + 16384;
        #pragma unroll
        for (int i = 0; i < 2; i++) {
            async16(gA + (size_t)i * 8 * 16384, As + (wid * 16 + i * 8) * 128);
            async16(gB + (size_t)i * 8 * 16384, Bs + (wid * 16 + i * 8) * 128);
        }
    }

    for (int it = 0; it < 128; it++) {
        __syncthreads();
        if (it + 1 < 128) {
            int kt = (it + 1) * 128;
            signed char* As = smem + ((it + 1) & 1) * 32768;
            signed char* Bs = As + 16384;
            #pragma unroll
            for (int i = 0; i < 2; i++) {
                async16(gA + (size_t)i * 8 * 16384 + kt, As + (wid * 16 + i * 8) * 128);
                async16(gB + (size_t)i * 8 * 16384 + kt, Bs + (wid * 16 + i * 8) * 128);
            }
        }
        const signed char* As = smem + (it & 1) * 32768;
        const signed char* Bs = As + 16384;
        #pragma unroll
        for (int ks = 0; ks < 2; ks++) {
            int sw = (((ks * 4) + (l >> 4)) ^ (l & 7)) * 16;
            v4i af[2], bf[4];
            #pragma unroll
            for (int i = 0; i < 2; i++)
                af[i] = *(const v4i*)&As[(wn0 + i * 16 + (l & 15)) * 128 + sw];
            #pragma unroll
            for (int q = 0; q < 4; q++)
                bf[q] = *(const v4i*)&Bs[(wj0 + q * 16 + (l & 15)) * 128 + sw];
            #pragma unroll
            for (int i = 0; i < 2; i++)
                #pragma unroll
                for (int q = 0; q < 4; q++)
                    acc[i][q] = __builtin_amdgcn_mfma_i32_16x16x64_i8(af[i], bf[q], acc[i][q], 0, 0, 0);
        }
    }

    __syncthreads();
    int* S = (int*)smem;
    #pragma unroll
    for (int i = 0; i < 2; i++)
        #pragma unroll
        for (int q = 0; q < 4; q++)
            #pragma unroll
            for (int rr = 0; rr < 4; rr++) {
                int n_l  = wn0 + i * 16 + (l >> 4) * 4 + rr;
                int jm_l = wj0 + q * 16 + (l & 15);
                S[n_l * 128 + jm_l] = acc[i][q][rr];
            }
    __syncthreads();

    const double SCALE = 1.0 / 4294967296.0;
    #pragma unroll
    for (int i = 0; i < 8; i++) {
        int idx = t * 8 + i;
        int n_l = idx >> 5, j_l = idx & 31;
        int4 s = *(const int4*)&S[n_l * 128 + j_l * 4];
        double val = (double)s.x + 128.0 * (double)s.y
                   + 16384.0 * (double)s.z + 2097152.0 * (double)s.w;
        int j = blockIdx.x * 32 + j_l;
        double p = val * SCALE + (double)fc1b[j];
        hs[(size_t)(nb0 + n_l) * 1024 + j] = (signed char)((p > 0.0) - (p < 0.0));
    }
}

__global__ void k5_fc2(const signed char* __restrict__ hs,
                       const float* __restrict__ fc2w, const float* __restrict__ fc2b,
                       float* __restrict__ out)
{
    int idx = blockIdx.x * 64 + threadIdx.x;
    if (idx >= 10240) return;
    int n = idx / 10, m = idx - n * 10;
    const signed char* hr = hs + (size_t)n * 1024;
    const float* wr = fc2w + (size_t)m * 1024;
    double acc = (double)fc2b[m];
    for (int jb = 0; jb < 1024; jb += 16) {
        int4 hv = *(const int4*)(hr + jb);
        int wd[4] = {hv.x, hv.y, hv.z, hv.w};
        #pragma unroll
        for (int u = 0; u < 4; u++)
            #pragma unroll
            for (int e = 0; e < 4; e++)
                acc += (double)(signed char)(wd[u] >> (8 * e)) * (double)wr[jb + u * 4 + e];
    }
    out[idx] = (float)acc;
}

extern "C" void kernel_launch(void* const* d_in, const int* in_sizes, int n_in,
                              void* d_out, int out_size, void* d_ws, size_t ws_size,
                              hipStream_t stream)
{
    const float* x    = (const float*)d_in[0];
    const float* w1dw = (const float*)d_in[1];
    const float* b1dw = (const float*)d_in[2];
    const float* w1pw = (const float*)d_in[3];
    const float* b1pw = (const float*)d_in[4];
    const float* w2dw = (const float*)d_in[5];
    const float* b2dw = (const float*)d_in[6];
    const float* w2pw = (const float*)d_in[7];
    const float* b2pw = (const float*)d_in[8];
    const float* fc1w = (const float*)d_in[9];
    const float* fc1b = (const float*)d_in[10];
    const float* fc2w = (const float*)d_in[11];
    const float* fc2b = (const float*)d_in[12];
    float* out = (float*)d_out;

    // workspace:
    //   BL       @0        64MiB   (written by k13c phase 3)
    //   hT2      @64MiB    16MiB
    //   w2s/b2adj@80MiB    33KB    (written by kprep2, read by k13c)
    //   hs       @80MiB+1M 1MiB    (fallback path only)
    //   Pd       @84934656 16MiB   fp64 K-split partials
    char* ws = (char*)d_ws;
    signed char* hT2      = (signed char*)(ws + 67108864);
    signed char* w2s      = (signed char*)(ws + 83886080);
    int*         b2adj    = (int*)(ws + 83886080 + 32768);
    signed char* BL       = (signed char*)(ws);
    signed char* hs       = (signed char*)(ws + 83886080 + 1048576);
    double*      Pd       = (double*)(ws + 84934656);
    bool split = ws_size >= (size_t)84934656 + 16777216;

    hipLaunchKernelGGL(kprep2,     dim3(4),    dim3(64),  0, stream,
                       w2pw, b2pw, w2s, b2adj);
    hipLaunchKernelGGL(k13c_fused, dim3(1024), dim3(512), 0, stream,
                       x, w1dw, b1dw, w1pw, b1pw, w2dw, b2dw, w2s, b2adj, hT2,
                       fc1w, BL);
    if (split) {
        hipLaunchKernelGGL(k4a_fc1,      dim3(16, 8, 2), dim3(512), 0, stream,
                           hT2, BL, Pd);
        hipLaunchKernelGGL(k45_comb_fc2, dim3(1024),     dim3(256), 0, stream,
                           Pd, fc1b, fc2w, fc2b, out);
    } else {
        hipLaunchKernelGGL(k4_fc1_mfma, dim3(32, 8), dim3(512), 0, stream,
                           hT2, BL, fc1b, hs);
        hipLaunchKernelGGL(k5_fc2,      dim3(160),   dim3(64),  0, stream,
                           hs, fc2w, fc2b, out);
    }
}